// Round 17
// baseline (488.201 us; speedup 1.0000x reference)
//
#include <hip/hip_runtime.h>

static constexpr int H = 4096;
static constexpr int W = 4096;
static constexpr long N = (long)H * W;

static constexpr int TX = 64;                // tile width  (cols)
static constexpr int TY = 128;               // tile height (rows)
static constexpr int HOFF = 12;              // halo; 10 needed + 2 slack
static constexpr int RX = TX + 2 * HOFF;     // 88
static constexpr int RY = TY + 2 * HOFF;     // 152
static constexpr int CPR = RX / 8;           // 11 chunks per row
static constexpr int PR  = RY / 2;           // 76 pair-rows
static constexpr int NTASK = PR * CPR;       // 836 tasks (16 px each)
static constexpr int PSE = PR * RX;          // 6688 halfs per half-plane
static constexpr int NT  = 1024;             // 16 waves; 2 blocks/CU = 32 waves/CU

static constexpr float SIGMA = 14.285714285714286f;  // 1/(7*0.01)
static constexpr float INVD  = 1.0f / 1.07f;
static constexpr float TIV   = 0.01f / 1.07f;        // TAU/(1+LT)
static constexpr float CF    = 0.07f / 1.07f;        // LAMBDA*TAU/(1+LT)

typedef _Float16 half8  __attribute__((ext_vector_type(8)));
typedef _Float16 half4v __attribute__((ext_vector_type(4)));

__device__ __forceinline__ half8 splat8(float f) {
    _Float16 h = (_Float16)f;
    half8 v = {h, h, h, h, h, h, h, h};
    return v;
}
__device__ __forceinline__ half8 clamp8(half8 v) {
    v = __builtin_elementwise_min(v, splat8(1.0f));
    v = __builtin_elementwise_max(v, splat8(-1.0f));
    return v;
}
__device__ __forceinline__ half4v lo4(half8 v) {
    half4v r = {v[0], v[1], v[2], v[3]}; return r;
}
__device__ __forceinline__ half4v hi4(half8 v) {
    half4v r = {v[4], v[5], v[6], v[7]}; return r;
}

// ---------------- pack: one linear pass over the fp32 inputs ----------------
// whp = SIGMA*w_h (0 at col W-1), wvp = SIGMA*w_v (0 at row H-1),
// cig = CF*img, xgi = fp16(img)   (xgi lives in d_out; scratch until phase1)
__global__ __launch_bounds__(256) void pack_all(
    const float* __restrict__ img, const float* __restrict__ wg,
    _Float16* __restrict__ whp, _Float16* __restrict__ wvp,
    _Float16* __restrict__ cig, _Float16* __restrict__ xgi)
{
    const long p = ((long)blockIdx.x * 256 + threadIdx.x) * 8;
    const int i = (int)(p >> 12);
    const float4* ip = reinterpret_cast<const float4*>(img + p);
    float4 m0 = ip[0], m1 = ip[1];
    const float4* hp = reinterpret_cast<const float4*>(wg + p);
    float4 a = hp[0], b = hp[1];
    const float4* vp = reinterpret_cast<const float4*>(wg + N + p);
    float4 c = vp[0], d = vp[1];
    float im[8] = {m0.x, m0.y, m0.z, m0.w, m1.x, m1.y, m1.z, m1.w};
    float wh[8] = {a.x, a.y, a.z, a.w, b.x, b.y, b.z, b.w};
    float wv[8] = {c.x, c.y, c.z, c.w, d.x, d.y, d.z, d.w};
    half8 whv, wvv, civ, xv;
#pragma unroll
    for (int k = 0; k < 8; ++k) {
        whv[k] = (_Float16)(SIGMA * wh[k]);
        wvv[k] = (_Float16)(SIGMA * wv[k]);
        civ[k] = (_Float16)(CF * im[k]);
        xv[k]  = (_Float16)im[k];
    }
    if ((p & 4095) + 8 == W) whv[7] = (_Float16)0.0f;  // gh BC at col W-1
    if (i == H - 1) wvv = splat8(0.0f);                // gv BC at row H-1
    *reinterpret_cast<half8*>(whp + p) = whv;
    *reinterpret_cast<half8*>(wvp + p) = wvv;
    *reinterpret_cast<half8*>(cig + p) = civ;
    *reinterpret_cast<half8*>(xgi + p) = xv;
}

// ---------------- phase kernel ----------------
// Vertical pairing: task t owns rows (2p, 2p+1), cols [j0, j0+8).
// In-register reuse: bv(row 2p) = xt1r, yva(row 2p+1) = yv0.
// LDS: even-row xt plane, odd-row yv plane, edge arrays (yh[7], odd xt[0]).
// PHASE 0: loads packed fp16 planes (warm); iters 0..9 + dual of iter 10;
//   stores centers {x, yh, yv}.
// PHASE 1: loads packed + state planes (warm); primal of iter 10 + iters
//   11..19; stores center xt fp32 into out (overwriting the xgi scratch).
// BCs data-encoded (w=0 outside image / col W-1 / row H-1); out-of-plane
// reads land on finite LDS and feed only cone-invalid halo pixels
// (margins: 12 >= 10+2; validated r4-r16).
template<int PHASE>
__global__ __launch_bounds__(NT, 2) void fused_pd(
    const _Float16* __restrict__ whp, const _Float16* __restrict__ wvp,
    const _Float16* __restrict__ cig, const _Float16* __restrict__ xgi,
    _Float16* __restrict__ xg, _Float16* __restrict__ yhg, _Float16* __restrict__ yvg,
    float* __restrict__ out)
{
    __shared__ _Float16 lds_s[2 * PSE + 3 * (NTASK + 2)];  // 31.8 KB
    _Float16* __restrict__ xte  = lds_s;                   // xt, even rows
    _Float16* __restrict__ yvo  = lds_s + PSE;             // yv, odd rows
    _Float16* __restrict__ yheA = lds_s + 2 * PSE;         // yh[7], row 2p, idx 1+t
    _Float16* __restrict__ yheB = yheA + (NTASK + 2);      // yh[7], row 2p+1
    _Float16* __restrict__ xteo = yheB + (NTASK + 2);      // xt[0], row 2p+1, idx t

    const int tid = threadIdx.x;
    const bool act = tid < NTASK;
    const int t  = act ? tid : 0;
    const int p  = t / CPR;
    const int j0 = (t - p * CPR) * 8;
    const int be = p * RX + j0;
    const int gi0 = blockIdx.y * TY - HOFF;
    const int gj0 = blockIdx.x * TX - HOFF;
    const bool interior = (gi0 >= 0) && (gj0 >= 0) && (gi0 + RY <= H) && (gj0 + RX <= W);

    const half8 kTIV  = splat8(TIV);
    const half8 kINVD = splat8(INVD);
    const half8 k15   = splat8(1.5f);
    const half8 kM05  = splat8(-0.5f);

    half8 wh0, wh1, wv0, wv1;   // SIGMA*w rows 2p, 2p+1 (BC-baked)
    half8 ci0, ci1;             // CF*img
    half8 x0, x1;               // primal state
    half8 xt0r, xt1r;           // own x_tilde
    half8 yh0, yh1, yv0, yv1;   // dual state

    auto loadRow = [&](int gi, int gj, half8& whr, half8& wvr, half8& cir,
                       half8& xr, half8& yhr, half8& yvr) {
        if (interior) {
            const long o = (long)gi * W + gj;
            whr = *reinterpret_cast<const half8*>(whp + o);
            wvr = *reinterpret_cast<const half8*>(wvp + o);
            cir = *reinterpret_cast<const half8*>(cig + o);
            if (PHASE == 0) {
                xr  = *reinterpret_cast<const half8*>(xgi + o);
                yhr = splat8(0.f); yvr = splat8(0.f);
            } else {
                xr  = *reinterpret_cast<const half8*>(xg  + o);
                yhr = *reinterpret_cast<const half8*>(yhg + o);
                yvr = *reinterpret_cast<const half8*>(yvg + o);
            }
        } else {
            const int gic = min(max(gi, 0), H - 1);
            const bool rowin = (gi >= 0) && (gi < H);
#pragma unroll
            for (int k = 0; k < 8; ++k) {
                const int gjk = gj + k;
                const int gjc = min(max(gjk, 0), W - 1);
                const bool inim = rowin && (gjk >= 0) && (gjk < W);
                const long o = (long)gic * W + gjc;
                whr[k] = inim ? whp[o] : (_Float16)0.0f;
                wvr[k] = inim ? wvp[o] : (_Float16)0.0f;
                cir[k] = cig[o];
                if (PHASE == 0) {
                    xr[k]  = xgi[o];
                    yhr[k] = (_Float16)0.0f;
                    yvr[k] = (_Float16)0.0f;
                } else {
                    xr[k]  = xg[o];
                    yhr[k] = inim ? yhg[o] : (_Float16)0.0f;
                    yvr[k] = inim ? yvg[o] : (_Float16)0.0f;
                }
            }
        }
    };
    if (act) {
        const int gi = gi0 + 2 * p;
        const int gj = gj0 + j0;
        loadRow(gi,     gj, wh0, wv0, ci0, x0, yh0, yv0);
        loadRow(gi + 1, gj, wh1, wv1, ci1, x1, yh1, yv1);
        if (PHASE == 0) {
            xt0r = x0; xt1r = x1;
            *reinterpret_cast<half8*>(xte + be) = xt0r;   // xt = img, even rows
            *reinterpret_cast<half8*>(yvo + be) = splat8(0.f);
            xteo[t] = xt1r[0];
            yheA[1 + t] = (_Float16)0.0f;
            yheB[1 + t] = (_Float16)0.0f;
        } else {
            *reinterpret_cast<half8*>(yvo + be) = yv1;
            yheA[1 + t] = yh0[7];
            yheB[1 + t] = yh1[7];
        }
    }
    if (tid == NT - 1) {
        yheA[0] = (_Float16)0.0f;
        yheB[0] = (_Float16)0.0f;
        xteo[NTASK]     = (_Float16)0.0f;
        xteo[NTASK + 1] = (_Float16)0.0f;
    }
    __syncthreads();

    // -------- dual: y = clamp(y + grad(xt)*SIGMA*w) --------
    auto dual_all = [&](bool writes) {
        if (act) {
            _Float16 rt0 = xte[be + 8];
            _Float16 rt1 = xteo[t + 1];
            half8 bv1 = *reinterpret_cast<const half8*>(xte + be + RX);
            half8 sh0 = __builtin_shufflevector(xt0r, xt0r, 1, 2, 3, 4, 5, 6, 7, 7);
            sh0[7] = rt0;
            half8 sh1 = __builtin_shufflevector(xt1r, xt1r, 1, 2, 3, 4, 5, 6, 7, 7);
            sh1[7] = rt1;
            yh0 = clamp8((sh0 - xt0r) * wh0 + yh0);
            yv0 = clamp8((xt1r - xt0r) * wv0 + yv0);    // bv(2p) = xt1r (reg)
            yh1 = clamp8((sh1 - xt1r) * wh1 + yh1);
            yv1 = clamp8((bv1 - xt1r) * wv1 + yv1);
            if (writes) {
                *reinterpret_cast<half8*>(yvo + be) = yv1;
                yheA[1 + t] = yh0[7];
                yheB[1 + t] = yh1[7];
            }
        }
    };
    // -------- primal: xn = x*INVD + (TIV*dv + ci); xt = 1.5*xn - 0.5*x --------
    auto prim_all = [&](bool writes) {
        if (act) {
            _Float16 yl0 = yheA[t];
            _Float16 yl1 = yheB[t];
            half8 yva0 = *reinterpret_cast<const half8*>(yvo + be - RX);
            half8 ysh0 = __builtin_shufflevector(yh0, yh0, 0, 0, 1, 2, 3, 4, 5, 6);
            ysh0[0] = yl0;
            half8 ysh1 = __builtin_shufflevector(yh1, yh1, 0, 0, 1, 2, 3, 4, 5, 6);
            ysh1[0] = yl1;
            half8 dv0 = (yh0 - ysh0) + (yv0 - yva0);
            half8 dv1 = (yh1 - ysh1) + (yv1 - yv0);     // yva(2p+1) = yv0 (reg)
            half8 tt0 = dv0 * kTIV + ci0;
            half8 xn0 = x0 * kINVD + tt0;
            half8 xtn0 = xn0 * k15 + x0 * kM05;
            x0 = xn0; xt0r = xtn0;
            half8 tt1 = dv1 * kTIV + ci1;
            half8 xn1 = x1 * kINVD + tt1;
            half8 xtn1 = xn1 * k15 + x1 * kM05;
            x1 = xn1; xt1r = xtn1;
            if (writes) {
                *reinterpret_cast<half8*>(xte + be) = xt0r;
                xteo[t] = xt1r[0];
            }
        }
    };

    if (PHASE == 1) {            // primal of iter 10 (dual-10 ran in phase0)
        prim_all(true);
        __syncthreads();
    }
    const int NIT = (PHASE == 0) ? 10 : 9;
    for (int it = 0; it < NIT; ++it) {
        dual_all(true);
        __syncthreads();
        prim_all(!(PHASE == 1 && it == NIT - 1));
        __syncthreads();
    }
    if (PHASE == 0) {            // dual of iter 10; no consumers -> no LDS writes
        dual_all(false);
    }

    // ---------------- stores (direct from registers) ----------------
    // center rows: p in [6, 6+TY/2); cols: j0==8 -> hi4, 16..64 full, 72 -> lo4.
    if (act && p >= 6 && p < 6 + TY / 2 && j0 >= 8 && j0 <= 72) {
        const long g0 = (long)(gi0 + 2 * p) * W + (gj0 + j0);
        const long g1 = g0 + W;
        if (PHASE == 0) {
            if (j0 >= 16 && j0 <= 64) {
                *reinterpret_cast<half8*>(xg  + g0) = x0;
                *reinterpret_cast<half8*>(xg  + g1) = x1;
                *reinterpret_cast<half8*>(yhg + g0) = yh0;
                *reinterpret_cast<half8*>(yhg + g1) = yh1;
                *reinterpret_cast<half8*>(yvg + g0) = yv0;
                *reinterpret_cast<half8*>(yvg + g1) = yv1;
            } else if (j0 == 8) {
                *reinterpret_cast<half4v*>(xg  + g0 + 4) = hi4(x0);
                *reinterpret_cast<half4v*>(xg  + g1 + 4) = hi4(x1);
                *reinterpret_cast<half4v*>(yhg + g0 + 4) = hi4(yh0);
                *reinterpret_cast<half4v*>(yhg + g1 + 4) = hi4(yh1);
                *reinterpret_cast<half4v*>(yvg + g0 + 4) = hi4(yv0);
                *reinterpret_cast<half4v*>(yvg + g1 + 4) = hi4(yv1);
            } else {  // j0 == 72
                *reinterpret_cast<half4v*>(xg  + g0) = lo4(x0);
                *reinterpret_cast<half4v*>(xg  + g1) = lo4(x1);
                *reinterpret_cast<half4v*>(yhg + g0) = lo4(yh0);
                *reinterpret_cast<half4v*>(yhg + g1) = lo4(yh1);
                *reinterpret_cast<half4v*>(yvg + g0) = lo4(yv0);
                *reinterpret_cast<half4v*>(yvg + g1) = lo4(yv1);
            }
        } else {
            float4 a0 = make_float4((float)xt0r[0], (float)xt0r[1], (float)xt0r[2], (float)xt0r[3]);
            float4 a1 = make_float4((float)xt0r[4], (float)xt0r[5], (float)xt0r[6], (float)xt0r[7]);
            float4 b0 = make_float4((float)xt1r[0], (float)xt1r[1], (float)xt1r[2], (float)xt1r[3]);
            float4 b1 = make_float4((float)xt1r[4], (float)xt1r[5], (float)xt1r[6], (float)xt1r[7]);
            if (j0 >= 16 && j0 <= 64) {
                *reinterpret_cast<float4*>(out + g0)     = a0;
                *reinterpret_cast<float4*>(out + g0 + 4) = a1;
                *reinterpret_cast<float4*>(out + g1)     = b0;
                *reinterpret_cast<float4*>(out + g1 + 4) = b1;
            } else if (j0 == 8) {
                *reinterpret_cast<float4*>(out + g0 + 4) = a1;
                *reinterpret_cast<float4*>(out + g1 + 4) = b1;
            } else {  // j0 == 72
                *reinterpret_cast<float4*>(out + g0) = a0;
                *reinterpret_cast<float4*>(out + g1) = b0;
            }
        }
    }
}

extern "C" void kernel_launch(void* const* d_in, const int* in_sizes, int n_in,
                              void* d_out, int out_size, void* d_ws, size_t ws_size,
                              hipStream_t stream) {
    const float* img = (const float*)d_in[0];   // (1,H,W)
    const float* wg  = (const float*)d_in[1];   // (2,H,W)
    float* out = (float*)d_out;

    // xgi (fp16 img) lives in the first 2N bytes of d_out; it is consumed by
    // phase0 only, and phase1 overwrites ALL of d_out with the fp32 result.
    _Float16* xgi = (_Float16*)d_out;

    _Float16* ws16 = (_Float16*)d_ws;           // 6 fp16 planes = 12N bytes
    _Float16* whp = ws16;
    _Float16* wvp = ws16 + N;
    _Float16* cig = ws16 + 2 * N;
    _Float16* xg  = ws16 + 3 * N;
    _Float16* yhg = ws16 + 4 * N;
    _Float16* yvg = ws16 + 5 * N;

    pack_all<<<dim3((int)(N / 8 / 256)), dim3(256), 0, stream>>>(img, wg, whp, wvp, cig, xgi);

    dim3 grid(W / TX, H / TY);                  // 64 x 32 = 2048 blocks (4 clean waves)
    fused_pd<0><<<grid, dim3(NT), 0, stream>>>(whp, wvp, cig, xgi, xg, yhg, yvg, out);
    fused_pd<1><<<grid, dim3(NT), 0, stream>>>(whp, wvp, cig, xgi, xg, yhg, yvg, out);
}

// Round 18
// 351.394 us; speedup vs baseline: 1.3893x; 1.3893x over previous
//
#include <hip/hip_runtime.h>

static constexpr int H = 4096;
static constexpr int W = 4096;
static constexpr long N = (long)H * W;

static constexpr int TILE = 64;
static constexpr int HOFF = 12;              // halo capacity; 10 needed + 2 slack
static constexpr int R    = TILE + 2*HOFF;   // 88
static constexpr int CPR  = R / 8;           // 11 chunks per row
static constexpr int PR   = R / 2;           // 44 pair-rows
static constexpr int NTASK= PR * CPR;        // 484 tasks (16 px each)
static constexpr int PSE  = PR * R;          // 3872 halfs per half-plane
static constexpr int NT   = 512;             // 8 waves; 4 blocks/CU

static constexpr float SIGMA = 14.285714285714286f;  // 1/(7*0.01)
static constexpr float INVD  = 1.0f / 1.07f;
static constexpr float TIV   = 0.01f / 1.07f;        // TAU/(1+LT)
static constexpr float CF    = 0.07f / 1.07f;        // LAMBDA*TAU/(1+LT)

typedef _Float16 half8  __attribute__((ext_vector_type(8)));
typedef _Float16 half4v __attribute__((ext_vector_type(4)));

__device__ __forceinline__ half8 splat8(float f) {
    _Float16 h = (_Float16)f;
    half8 v = {h, h, h, h, h, h, h, h};
    return v;
}
__device__ __forceinline__ half8 clamp8(half8 v) {
    v = __builtin_elementwise_min(v, splat8(1.0f));
    v = __builtin_elementwise_max(v, splat8(-1.0f));
    return v;
}
__device__ __forceinline__ half4v lo4(half8 v) {
    half4v r = {v[0], v[1], v[2], v[3]}; return r;
}
__device__ __forceinline__ half4v hi4(half8 v) {
    half4v r = {v[4], v[5], v[6], v[7]}; return r;
}

// ---------------- pack: whp = SIGMA*w_h (0 at col W-1), wvp = SIGMA*w_v
// (0 at row H-1), cig = CF*img.  One linear pass over the fp32 inputs.
__global__ __launch_bounds__(256) void pack_w(
    const float* __restrict__ img, const float* __restrict__ wg,
    _Float16* __restrict__ whp, _Float16* __restrict__ wvp, _Float16* __restrict__ cig)
{
    const long p = ((long)blockIdx.x * 256 + threadIdx.x) * 8;
    const int i = (int)(p >> 12);
    const float4* ip = reinterpret_cast<const float4*>(img + p);
    float4 m0 = ip[0], m1 = ip[1];
    const float4* hp = reinterpret_cast<const float4*>(wg + p);
    float4 a = hp[0], b = hp[1];
    const float4* vp = reinterpret_cast<const float4*>(wg + N + p);
    float4 c = vp[0], d = vp[1];
    float im[8] = {m0.x, m0.y, m0.z, m0.w, m1.x, m1.y, m1.z, m1.w};
    float wh[8] = {a.x, a.y, a.z, a.w, b.x, b.y, b.z, b.w};
    float wv[8] = {c.x, c.y, c.z, c.w, d.x, d.y, d.z, d.w};
    half8 whv, wvv, civ;
#pragma unroll
    for (int k = 0; k < 8; ++k) {
        whv[k] = (_Float16)(SIGMA * wh[k]);
        wvv[k] = (_Float16)(SIGMA * wv[k]);
        civ[k] = (_Float16)(CF * im[k]);
    }
    if ((p & 4095) + 8 == W) whv[7] = (_Float16)0.0f;  // gh BC at col W-1
    if (i == H - 1) wvv = splat8(0.0f);                // gv BC at row H-1
    *reinterpret_cast<half8*>(whp + p) = whv;
    *reinterpret_cast<half8*>(wvp + p) = wvv;
    *reinterpret_cast<half8*>(cig + p) = civ;
}

// ---------------- phase kernel ----------------
// Vertical pairing: task t owns rows (2p, 2p+1), cols [j0, j0+8).
// In-register reuse: bv(row 2p) = xt1r, yva(row 2p+1) = yv0.
// LDS: even-row xt plane, odd-row yv plane, edge arrays (yh[7], odd xt[0]).
// PHASE 0: reads img fp32 (x init + ci in regs); iters 0..9 + dual of iter
//   10; stores centers {x, yh, yv}.
// PHASE 1: reads warm fp16 planes only (cig instead of img); primal of iter
//   10 + iters 11..19; stores center xt fp32.
// BCs data-encoded (w=0 outside image / col W-1 / row H-1); out-of-plane
// reads land on finite LDS and feed only cone-invalid halo pixels
// (margins: 12 >= 10+2; validated r4-r16).
template<int PHASE>
__global__ __launch_bounds__(NT, 4) void fused_pd(
    const float* __restrict__ img,
    const _Float16* __restrict__ whp, const _Float16* __restrict__ wvp,
    const _Float16* __restrict__ cig,
    _Float16* __restrict__ xg, _Float16* __restrict__ yhg, _Float16* __restrict__ yvg,
    float* __restrict__ out)
{
    __shared__ _Float16 lds_s[2 * PSE + 3 * (NTASK + 2)];  // 18.4 KB
    _Float16* __restrict__ xte  = lds_s;                   // xt, even rows
    _Float16* __restrict__ yvo  = lds_s + PSE;             // yv, odd rows
    _Float16* __restrict__ yheA = lds_s + 2 * PSE;         // yh[7], row 2p, idx 1+t
    _Float16* __restrict__ yheB = yheA + (NTASK + 2);      // yh[7], row 2p+1
    _Float16* __restrict__ xteo = yheB + (NTASK + 2);      // xt[0], row 2p+1, idx t

    const int tid = threadIdx.x;
    const bool act = tid < NTASK;
    const int t  = act ? tid : 0;
    const int p  = t / CPR;
    const int j0 = (t - p * CPR) * 8;
    const int be = p * R + j0;
    const int gi0 = blockIdx.y * TILE - HOFF;
    const int gj0 = blockIdx.x * TILE - HOFF;
    const bool interior = (gi0 >= 0) && (gj0 >= 0) && (gi0 + R <= H) && (gj0 + R <= W);

    const half8 kTIV  = splat8(TIV);
    const half8 kINVD = splat8(INVD);
    const half8 k15   = splat8(1.5f);
    const half8 kM05  = splat8(-0.5f);

    half8 wh0, wh1, wv0, wv1;   // SIGMA*w rows 2p, 2p+1 (BC-baked)
    half8 ci0, ci1;             // CF*img
    half8 x0, x1;               // primal state
    half8 xt0r, xt1r;           // own x_tilde
    half8 yh0, yh1, yv0, yv1;   // dual state

    auto loadRow = [&](int gi, int gj, half8& whr, half8& wvr, half8& cir,
                       half8& xr, half8& yhr, half8& yvr) {
        if (interior) {
            const long o = (long)gi * W + gj;
            whr = *reinterpret_cast<const half8*>(whp + o);
            wvr = *reinterpret_cast<const half8*>(wvp + o);
            if (PHASE == 0) {
                const float4* ip = reinterpret_cast<const float4*>(img + o);
                float4 a = ip[0], b = ip[1];
                float im[8] = {a.x, a.y, a.z, a.w, b.x, b.y, b.z, b.w};
#pragma unroll
                for (int k = 0; k < 8; ++k) {
                    cir[k] = (_Float16)(CF * im[k]);
                    xr[k]  = (_Float16)im[k];
                }
                yhr = splat8(0.f); yvr = splat8(0.f);
            } else {
                cir = *reinterpret_cast<const half8*>(cig + o);
                xr  = *reinterpret_cast<const half8*>(xg  + o);
                yhr = *reinterpret_cast<const half8*>(yhg + o);
                yvr = *reinterpret_cast<const half8*>(yvg + o);
            }
        } else {
            const int gic = min(max(gi, 0), H - 1);
            const bool rowin = (gi >= 0) && (gi < H);
#pragma unroll
            for (int k = 0; k < 8; ++k) {
                const int gjk = gj + k;
                const int gjc = min(max(gjk, 0), W - 1);
                const bool inim = rowin && (gjk >= 0) && (gjk < W);
                const long o = (long)gic * W + gjc;
                whr[k] = inim ? whp[o] : (_Float16)0.0f;
                wvr[k] = inim ? wvp[o] : (_Float16)0.0f;
                if (PHASE == 0) {
                    const float imf = img[o];
                    cir[k] = (_Float16)(CF * imf);
                    xr[k]  = (_Float16)imf;
                    yhr[k] = (_Float16)0.0f;
                    yvr[k] = (_Float16)0.0f;
                } else {
                    cir[k] = cig[o];
                    xr[k]  = xg[o];
                    yhr[k] = inim ? yhg[o] : (_Float16)0.0f;
                    yvr[k] = inim ? yvg[o] : (_Float16)0.0f;
                }
            }
        }
    };
    if (act) {
        const int gi = gi0 + 2 * p;
        const int gj = gj0 + j0;
        loadRow(gi,     gj, wh0, wv0, ci0, x0, yh0, yv0);
        loadRow(gi + 1, gj, wh1, wv1, ci1, x1, yh1, yv1);
        if (PHASE == 0) {
            xt0r = x0; xt1r = x1;
            *reinterpret_cast<half8*>(xte + be) = xt0r;   // xt = img, even rows
            *reinterpret_cast<half8*>(yvo + be) = splat8(0.f);
            xteo[t] = xt1r[0];
            yheA[1 + t] = (_Float16)0.0f;
            yheB[1 + t] = (_Float16)0.0f;
        } else {
            *reinterpret_cast<half8*>(yvo + be) = yv1;
            yheA[1 + t] = yh0[7];
            yheB[1 + t] = yh1[7];
        }
    }
    if (tid == NT - 1) {
        yheA[0] = (_Float16)0.0f;
        yheB[0] = (_Float16)0.0f;
        xteo[NTASK]     = (_Float16)0.0f;
        xteo[NTASK + 1] = (_Float16)0.0f;
    }
    __syncthreads();

    // -------- dual: y = clamp(y + grad(xt)*SIGMA*w) --------
    auto dual_all = [&](bool writes) {
        if (act) {
            _Float16 rt0 = xte[be + 8];
            _Float16 rt1 = xteo[t + 1];
            half8 bv1 = *reinterpret_cast<const half8*>(xte + be + R);
            half8 sh0 = __builtin_shufflevector(xt0r, xt0r, 1, 2, 3, 4, 5, 6, 7, 7);
            sh0[7] = rt0;
            half8 sh1 = __builtin_shufflevector(xt1r, xt1r, 1, 2, 3, 4, 5, 6, 7, 7);
            sh1[7] = rt1;
            yh0 = clamp8((sh0 - xt0r) * wh0 + yh0);
            yv0 = clamp8((xt1r - xt0r) * wv0 + yv0);    // bv(2p) = xt1r (reg)
            yh1 = clamp8((sh1 - xt1r) * wh1 + yh1);
            yv1 = clamp8((bv1 - xt1r) * wv1 + yv1);
            if (writes) {
                *reinterpret_cast<half8*>(yvo + be) = yv1;
                yheA[1 + t] = yh0[7];
                yheB[1 + t] = yh1[7];
            }
        }
    };
    // -------- primal: xn = x*INVD + (TIV*dv + ci); xt = 1.5*xn - 0.5*x --------
    auto prim_all = [&](bool writes) {
        if (act) {
            _Float16 yl0 = yheA[t];
            _Float16 yl1 = yheB[t];
            half8 yva0 = *reinterpret_cast<const half8*>(yvo + be - R);
            half8 ysh0 = __builtin_shufflevector(yh0, yh0, 0, 0, 1, 2, 3, 4, 5, 6);
            ysh0[0] = yl0;
            half8 ysh1 = __builtin_shufflevector(yh1, yh1, 0, 0, 1, 2, 3, 4, 5, 6);
            ysh1[0] = yl1;
            half8 dv0 = (yh0 - ysh0) + (yv0 - yva0);
            half8 dv1 = (yh1 - ysh1) + (yv1 - yv0);     // yva(2p+1) = yv0 (reg)
            half8 tt0 = dv0 * kTIV + ci0;
            half8 xn0 = x0 * kINVD + tt0;
            half8 xtn0 = xn0 * k15 + x0 * kM05;
            x0 = xn0; xt0r = xtn0;
            half8 tt1 = dv1 * kTIV + ci1;
            half8 xn1 = x1 * kINVD + tt1;
            half8 xtn1 = xn1 * k15 + x1 * kM05;
            x1 = xn1; xt1r = xtn1;
            if (writes) {
                *reinterpret_cast<half8*>(xte + be) = xt0r;
                xteo[t] = xt1r[0];
            }
        }
    };

    if (PHASE == 1) {            // primal of iter 10 (dual-10 ran in phase0)
        prim_all(true);
        __syncthreads();
    }
    const int NIT = (PHASE == 0) ? 10 : 9;
    for (int it = 0; it < NIT; ++it) {
        dual_all(true);
        __syncthreads();
        prim_all(!(PHASE == 1 && it == NIT - 1));
        __syncthreads();
    }
    if (PHASE == 0) {            // dual of iter 10; no consumers -> no LDS writes
        dual_all(false);
    }

    // ---------------- stores (direct from registers) ----------------
    // center rows: p in [6,38); cols: j0==8 -> hi4, 16..64 -> full, 72 -> lo4.
    if (act && p >= 6 && p < 38 && j0 >= 8 && j0 <= 72) {
        const long g0 = (long)(gi0 + 2 * p) * W + (gj0 + j0);
        const long g1 = g0 + W;
        if (PHASE == 0) {
            if (j0 >= 16 && j0 <= 64) {
                *reinterpret_cast<half8*>(xg  + g0) = x0;
                *reinterpret_cast<half8*>(xg  + g1) = x1;
                *reinterpret_cast<half8*>(yhg + g0) = yh0;
                *reinterpret_cast<half8*>(yhg + g1) = yh1;
                *reinterpret_cast<half8*>(yvg + g0) = yv0;
                *reinterpret_cast<half8*>(yvg + g1) = yv1;
            } else if (j0 == 8) {
                *reinterpret_cast<half4v*>(xg  + g0 + 4) = hi4(x0);
                *reinterpret_cast<half4v*>(xg  + g1 + 4) = hi4(x1);
                *reinterpret_cast<half4v*>(yhg + g0 + 4) = hi4(yh0);
                *reinterpret_cast<half4v*>(yhg + g1 + 4) = hi4(yh1);
                *reinterpret_cast<half4v*>(yvg + g0 + 4) = hi4(yv0);
                *reinterpret_cast<half4v*>(yvg + g1 + 4) = hi4(yv1);
            } else {  // j0 == 72
                *reinterpret_cast<half4v*>(xg  + g0) = lo4(x0);
                *reinterpret_cast<half4v*>(xg  + g1) = lo4(x1);
                *reinterpret_cast<half4v*>(yhg + g0) = lo4(yh0);
                *reinterpret_cast<half4v*>(yhg + g1) = lo4(yh1);
                *reinterpret_cast<half4v*>(yvg + g0) = lo4(yv0);
                *reinterpret_cast<half4v*>(yvg + g1) = lo4(yv1);
            }
        } else {
            float4 a0 = make_float4((float)xt0r[0], (float)xt0r[1], (float)xt0r[2], (float)xt0r[3]);
            float4 a1 = make_float4((float)xt0r[4], (float)xt0r[5], (float)xt0r[6], (float)xt0r[7]);
            float4 b0 = make_float4((float)xt1r[0], (float)xt1r[1], (float)xt1r[2], (float)xt1r[3]);
            float4 b1 = make_float4((float)xt1r[4], (float)xt1r[5], (float)xt1r[6], (float)xt1r[7]);
            if (j0 >= 16 && j0 <= 64) {
                *reinterpret_cast<float4*>(out + g0)     = a0;
                *reinterpret_cast<float4*>(out + g0 + 4) = a1;
                *reinterpret_cast<float4*>(out + g1)     = b0;
                *reinterpret_cast<float4*>(out + g1 + 4) = b1;
            } else if (j0 == 8) {
                *reinterpret_cast<float4*>(out + g0 + 4) = a1;
                *reinterpret_cast<float4*>(out + g1 + 4) = b1;
            } else {  // j0 == 72
                *reinterpret_cast<float4*>(out + g0) = a0;
                *reinterpret_cast<float4*>(out + g1) = b0;
            }
        }
    }
}

extern "C" void kernel_launch(void* const* d_in, const int* in_sizes, int n_in,
                              void* d_out, int out_size, void* d_ws, size_t ws_size,
                              hipStream_t stream) {
    const float* img = (const float*)d_in[0];   // (1,H,W)
    const float* wg  = (const float*)d_in[1];   // (2,H,W)
    float* out = (float*)d_out;

    _Float16* ws16 = (_Float16*)d_ws;           // 6 fp16 planes = 12N bytes
    _Float16* whp = ws16;
    _Float16* wvp = ws16 + N;
    _Float16* cig = ws16 + 2 * N;
    _Float16* xg  = ws16 + 3 * N;
    _Float16* yhg = ws16 + 4 * N;
    _Float16* yvg = ws16 + 5 * N;

    pack_w<<<dim3((int)(N / 8 / 256)), dim3(256), 0, stream>>>(img, wg, whp, wvp, cig);

    dim3 grid(W / TILE, H / TILE);              // 64 x 64 = 4096 blocks
    fused_pd<0><<<grid, dim3(NT), 0, stream>>>(img, whp, wvp, cig, xg, yhg, yvg, out);
    fused_pd<1><<<grid, dim3(NT), 0, stream>>>(img, whp, wvp, cig, xg, yhg, yvg, out);
}

// Round 19
// 337.244 us; speedup vs baseline: 1.4476x; 1.0420x over previous
//
#include <hip/hip_runtime.h>

static constexpr int H = 4096;
static constexpr int W = 4096;
static constexpr long N = (long)H * W;

static constexpr int TILE = 64;
static constexpr int HOFF = 12;              // halo capacity; 10 needed + 2 slack
static constexpr int R    = TILE + 2*HOFF;   // 88
static constexpr int CPR  = R / 8;           // 11 chunks per row
static constexpr int PR   = R / 2;           // 44 pair-rows
static constexpr int NTASK= PR * CPR;        // 484 tasks (16 px each)
static constexpr int PSE  = PR * R;          // 3872 halfs per half-plane
static constexpr int NT   = 512;             // 8 waves; 4 blocks/CU

static constexpr float SIGMA = 14.285714285714286f;  // 1/(7*0.01)
static constexpr float INVD  = 1.0f / 1.07f;
static constexpr float TIV   = 0.01f / 1.07f;        // TAU/(1+LT)
static constexpr float CF    = 0.07f / 1.07f;        // LAMBDA*TAU/(1+LT)

typedef _Float16 half8  __attribute__((ext_vector_type(8)));
typedef _Float16 half4v __attribute__((ext_vector_type(4)));

__device__ __forceinline__ half8 splat8(float f) {
    _Float16 h = (_Float16)f;
    half8 v = {h, h, h, h, h, h, h, h};
    return v;
}
__device__ __forceinline__ half8 clamp8(half8 v) {
    v = __builtin_elementwise_min(v, splat8(1.0f));
    v = __builtin_elementwise_max(v, splat8(-1.0f));
    return v;
}
__device__ __forceinline__ half4v lo4(half8 v) {
    half4v r = {v[0], v[1], v[2], v[3]}; return r;
}
__device__ __forceinline__ half4v hi4(half8 v) {
    half4v r = {v[4], v[5], v[6], v[7]}; return r;
}

// ---------------- pack: whp = SIGMA*w_h (0 at col W-1), wvp = SIGMA*w_v
// (0 at row H-1). One linear pass over w only (img handled by phase0).
__global__ __launch_bounds__(256) void pack_w(
    const float* __restrict__ wg,
    _Float16* __restrict__ whp, _Float16* __restrict__ wvp)
{
    const long p = ((long)blockIdx.x * 256 + threadIdx.x) * 8;
    const int i = (int)(p >> 12);
    const float4* hp = reinterpret_cast<const float4*>(wg + p);
    float4 a = hp[0], b = hp[1];
    const float4* vp = reinterpret_cast<const float4*>(wg + N + p);
    float4 c = vp[0], d = vp[1];
    float wh[8] = {a.x, a.y, a.z, a.w, b.x, b.y, b.z, b.w};
    float wv[8] = {c.x, c.y, c.z, c.w, d.x, d.y, d.z, d.w};
    half8 whv, wvv;
#pragma unroll
    for (int k = 0; k < 8; ++k) {
        whv[k] = (_Float16)(SIGMA * wh[k]);
        wvv[k] = (_Float16)(SIGMA * wv[k]);
    }
    if ((p & 4095) + 8 == W) whv[7] = (_Float16)0.0f;  // gh BC at col W-1
    if (i == H - 1) wvv = splat8(0.0f);                // gv BC at row H-1
    *reinterpret_cast<half8*>(whp + p) = whv;
    *reinterpret_cast<half8*>(wvp + p) = wvv;
}

// ---------------- phase kernel ----------------
// Vertical pairing: task t owns rows (2p, 2p+1), cols [j0, j0+8).
// In-register reuse: bv(row 2p) = xt1r, yva(row 2p+1) = yv0.
// LDS: even-row xt plane, odd-row yv plane, edge arrays (yh[7], odd xt[0]).
// PHASE 0: reads img fp32 + packed w (x init + ci in regs); iters 0..9 +
//   dual of iter 10; stores centers {x, yh, yv, cig} -- cig written here so
//   ALL of phase1's reads are L3-fresh (r18 lesson: pack-written cig was
//   the LRU eviction victim during phase0's streaming).
// PHASE 1: reads warm fp16 planes only; primal of iter 10 + iters 11..19;
//   stores center xt fp32.
// BCs data-encoded (w=0 outside image / col W-1 / row H-1); out-of-plane
// reads land on finite LDS and feed only cone-invalid halo pixels
// (margins: 12 >= 10+2; validated r4-r18).
template<int PHASE>
__global__ __launch_bounds__(NT, 4) void fused_pd(
    const float* __restrict__ img,
    const _Float16* __restrict__ whp, const _Float16* __restrict__ wvp,
    _Float16* __restrict__ cig,
    _Float16* __restrict__ xg, _Float16* __restrict__ yhg, _Float16* __restrict__ yvg,
    float* __restrict__ out)
{
    __shared__ _Float16 lds_s[2 * PSE + 3 * (NTASK + 2)];  // 18.4 KB
    _Float16* __restrict__ xte  = lds_s;                   // xt, even rows
    _Float16* __restrict__ yvo  = lds_s + PSE;             // yv, odd rows
    _Float16* __restrict__ yheA = lds_s + 2 * PSE;         // yh[7], row 2p, idx 1+t
    _Float16* __restrict__ yheB = yheA + (NTASK + 2);      // yh[7], row 2p+1
    _Float16* __restrict__ xteo = yheB + (NTASK + 2);      // xt[0], row 2p+1, idx t

    const int tid = threadIdx.x;
    const bool act = tid < NTASK;
    const int t  = act ? tid : 0;
    const int p  = t / CPR;
    const int j0 = (t - p * CPR) * 8;
    const int be = p * R + j0;
    const int gi0 = blockIdx.y * TILE - HOFF;
    const int gj0 = blockIdx.x * TILE - HOFF;
    const bool interior = (gi0 >= 0) && (gj0 >= 0) && (gi0 + R <= H) && (gj0 + R <= W);

    const half8 kTIV  = splat8(TIV);
    const half8 kINVD = splat8(INVD);
    const half8 k15   = splat8(1.5f);
    const half8 kM05  = splat8(-0.5f);

    half8 wh0, wh1, wv0, wv1;   // SIGMA*w rows 2p, 2p+1 (BC-baked)
    half8 ci0, ci1;             // CF*img
    half8 x0, x1;               // primal state
    half8 xt0r, xt1r;           // own x_tilde
    half8 yh0, yh1, yv0, yv1;   // dual state

    auto loadRow = [&](int gi, int gj, half8& whr, half8& wvr, half8& cir,
                       half8& xr, half8& yhr, half8& yvr) {
        if (interior) {
            const long o = (long)gi * W + gj;
            whr = *reinterpret_cast<const half8*>(whp + o);
            wvr = *reinterpret_cast<const half8*>(wvp + o);
            if (PHASE == 0) {
                const float4* ip = reinterpret_cast<const float4*>(img + o);
                float4 a = ip[0], b = ip[1];
                float im[8] = {a.x, a.y, a.z, a.w, b.x, b.y, b.z, b.w};
#pragma unroll
                for (int k = 0; k < 8; ++k) {
                    cir[k] = (_Float16)(CF * im[k]);
                    xr[k]  = (_Float16)im[k];
                }
                yhr = splat8(0.f); yvr = splat8(0.f);
            } else {
                cir = *reinterpret_cast<const half8*>(cig + o);
                xr  = *reinterpret_cast<const half8*>(xg  + o);
                yhr = *reinterpret_cast<const half8*>(yhg + o);
                yvr = *reinterpret_cast<const half8*>(yvg + o);
            }
        } else {
            const int gic = min(max(gi, 0), H - 1);
            const bool rowin = (gi >= 0) && (gi < H);
#pragma unroll
            for (int k = 0; k < 8; ++k) {
                const int gjk = gj + k;
                const int gjc = min(max(gjk, 0), W - 1);
                const bool inim = rowin && (gjk >= 0) && (gjk < W);
                const long o = (long)gic * W + gjc;
                whr[k] = inim ? whp[o] : (_Float16)0.0f;
                wvr[k] = inim ? wvp[o] : (_Float16)0.0f;
                if (PHASE == 0) {
                    const float imf = img[o];
                    cir[k] = (_Float16)(CF * imf);
                    xr[k]  = (_Float16)imf;
                    yhr[k] = (_Float16)0.0f;
                    yvr[k] = (_Float16)0.0f;
                } else {
                    cir[k] = cig[o];
                    xr[k]  = xg[o];
                    yhr[k] = inim ? yhg[o] : (_Float16)0.0f;
                    yvr[k] = inim ? yvg[o] : (_Float16)0.0f;
                }
            }
        }
    };
    if (act) {
        const int gi = gi0 + 2 * p;
        const int gj = gj0 + j0;
        loadRow(gi,     gj, wh0, wv0, ci0, x0, yh0, yv0);
        loadRow(gi + 1, gj, wh1, wv1, ci1, x1, yh1, yv1);
        if (PHASE == 0) {
            xt0r = x0; xt1r = x1;
            *reinterpret_cast<half8*>(xte + be) = xt0r;   // xt = img, even rows
            *reinterpret_cast<half8*>(yvo + be) = splat8(0.f);
            xteo[t] = xt1r[0];
            yheA[1 + t] = (_Float16)0.0f;
            yheB[1 + t] = (_Float16)0.0f;
        } else {
            *reinterpret_cast<half8*>(yvo + be) = yv1;
            yheA[1 + t] = yh0[7];
            yheB[1 + t] = yh1[7];
        }
    }
    if (tid == NT - 1) {
        yheA[0] = (_Float16)0.0f;
        yheB[0] = (_Float16)0.0f;
        xteo[NTASK]     = (_Float16)0.0f;
        xteo[NTASK + 1] = (_Float16)0.0f;
    }
    __syncthreads();

    // -------- dual: y = clamp(y + grad(xt)*SIGMA*w) --------
    auto dual_all = [&](bool writes) {
        if (act) {
            _Float16 rt0 = xte[be + 8];
            _Float16 rt1 = xteo[t + 1];
            half8 bv1 = *reinterpret_cast<const half8*>(xte + be + R);
            half8 sh0 = __builtin_shufflevector(xt0r, xt0r, 1, 2, 3, 4, 5, 6, 7, 7);
            sh0[7] = rt0;
            half8 sh1 = __builtin_shufflevector(xt1r, xt1r, 1, 2, 3, 4, 5, 6, 7, 7);
            sh1[7] = rt1;
            yh0 = clamp8((sh0 - xt0r) * wh0 + yh0);
            yv0 = clamp8((xt1r - xt0r) * wv0 + yv0);    // bv(2p) = xt1r (reg)
            yh1 = clamp8((sh1 - xt1r) * wh1 + yh1);
            yv1 = clamp8((bv1 - xt1r) * wv1 + yv1);
            if (writes) {
                *reinterpret_cast<half8*>(yvo + be) = yv1;
                yheA[1 + t] = yh0[7];
                yheB[1 + t] = yh1[7];
            }
        }
    };
    // -------- primal: xn = x*INVD + (TIV*dv + ci); xt = 1.5*xn - 0.5*x --------
    auto prim_all = [&](bool writes) {
        if (act) {
            _Float16 yl0 = yheA[t];
            _Float16 yl1 = yheB[t];
            half8 yva0 = *reinterpret_cast<const half8*>(yvo + be - R);
            half8 ysh0 = __builtin_shufflevector(yh0, yh0, 0, 0, 1, 2, 3, 4, 5, 6);
            ysh0[0] = yl0;
            half8 ysh1 = __builtin_shufflevector(yh1, yh1, 0, 0, 1, 2, 3, 4, 5, 6);
            ysh1[0] = yl1;
            half8 dv0 = (yh0 - ysh0) + (yv0 - yva0);
            half8 dv1 = (yh1 - ysh1) + (yv1 - yv0);     // yva(2p+1) = yv0 (reg)
            half8 tt0 = dv0 * kTIV + ci0;
            half8 xn0 = x0 * kINVD + tt0;
            half8 xtn0 = xn0 * k15 + x0 * kM05;
            x0 = xn0; xt0r = xtn0;
            half8 tt1 = dv1 * kTIV + ci1;
            half8 xn1 = x1 * kINVD + tt1;
            half8 xtn1 = xn1 * k15 + x1 * kM05;
            x1 = xn1; xt1r = xtn1;
            if (writes) {
                *reinterpret_cast<half8*>(xte + be) = xt0r;
                xteo[t] = xt1r[0];
            }
        }
    };

    if (PHASE == 1) {            // primal of iter 10 (dual-10 ran in phase0)
        prim_all(true);
        __syncthreads();
    }
    const int NIT = (PHASE == 0) ? 10 : 9;
    for (int it = 0; it < NIT; ++it) {
        dual_all(true);
        __syncthreads();
        prim_all(!(PHASE == 1 && it == NIT - 1));
        __syncthreads();
    }
    if (PHASE == 0) {            // dual of iter 10; no consumers -> no LDS writes
        dual_all(false);
    }

    // ---------------- stores (direct from registers) ----------------
    // center rows: p in [6,38); cols: j0==8 -> hi4, 16..64 -> full, 72 -> lo4.
    if (act && p >= 6 && p < 38 && j0 >= 8 && j0 <= 72) {
        const long g0 = (long)(gi0 + 2 * p) * W + (gj0 + j0);
        const long g1 = g0 + W;
        if (PHASE == 0) {
            if (j0 >= 16 && j0 <= 64) {
                *reinterpret_cast<half8*>(xg  + g0) = x0;
                *reinterpret_cast<half8*>(xg  + g1) = x1;
                *reinterpret_cast<half8*>(yhg + g0) = yh0;
                *reinterpret_cast<half8*>(yhg + g1) = yh1;
                *reinterpret_cast<half8*>(yvg + g0) = yv0;
                *reinterpret_cast<half8*>(yvg + g1) = yv1;
                *reinterpret_cast<half8*>(cig + g0) = ci0;
                *reinterpret_cast<half8*>(cig + g1) = ci1;
            } else if (j0 == 8) {
                *reinterpret_cast<half4v*>(xg  + g0 + 4) = hi4(x0);
                *reinterpret_cast<half4v*>(xg  + g1 + 4) = hi4(x1);
                *reinterpret_cast<half4v*>(yhg + g0 + 4) = hi4(yh0);
                *reinterpret_cast<half4v*>(yhg + g1 + 4) = hi4(yh1);
                *reinterpret_cast<half4v*>(yvg + g0 + 4) = hi4(yv0);
                *reinterpret_cast<half4v*>(yvg + g1 + 4) = hi4(yv1);
                *reinterpret_cast<half4v*>(cig + g0 + 4) = hi4(ci0);
                *reinterpret_cast<half4v*>(cig + g1 + 4) = hi4(ci1);
            } else {  // j0 == 72
                *reinterpret_cast<half4v*>(xg  + g0) = lo4(x0);
                *reinterpret_cast<half4v*>(xg  + g1) = lo4(x1);
                *reinterpret_cast<half4v*>(yhg + g0) = lo4(yh0);
                *reinterpret_cast<half4v*>(yhg + g1) = lo4(yh1);
                *reinterpret_cast<half4v*>(yvg + g0) = lo4(yv0);
                *reinterpret_cast<half4v*>(yvg + g1) = lo4(yv1);
                *reinterpret_cast<half4v*>(cig + g0) = lo4(ci0);
                *reinterpret_cast<half4v*>(cig + g1) = lo4(ci1);
            }
        } else {
            float4 a0 = make_float4((float)xt0r[0], (float)xt0r[1], (float)xt0r[2], (float)xt0r[3]);
            float4 a1 = make_float4((float)xt0r[4], (float)xt0r[5], (float)xt0r[6], (float)xt0r[7]);
            float4 b0 = make_float4((float)xt1r[0], (float)xt1r[1], (float)xt1r[2], (float)xt1r[3]);
            float4 b1 = make_float4((float)xt1r[4], (float)xt1r[5], (float)xt1r[6], (float)xt1r[7]);
            if (j0 >= 16 && j0 <= 64) {
                *reinterpret_cast<float4*>(out + g0)     = a0;
                *reinterpret_cast<float4*>(out + g0 + 4) = a1;
                *reinterpret_cast<float4*>(out + g1)     = b0;
                *reinterpret_cast<float4*>(out + g1 + 4) = b1;
            } else if (j0 == 8) {
                *reinterpret_cast<float4*>(out + g0 + 4) = a1;
                *reinterpret_cast<float4*>(out + g1 + 4) = b1;
            } else {  // j0 == 72
                *reinterpret_cast<float4*>(out + g0) = a0;
                *reinterpret_cast<float4*>(out + g1) = b0;
            }
        }
    }
}

extern "C" void kernel_launch(void* const* d_in, const int* in_sizes, int n_in,
                              void* d_out, int out_size, void* d_ws, size_t ws_size,
                              hipStream_t stream) {
    const float* img = (const float*)d_in[0];   // (1,H,W)
    const float* wg  = (const float*)d_in[1];   // (2,H,W)
    float* out = (float*)d_out;

    _Float16* ws16 = (_Float16*)d_ws;           // 6 fp16 planes = 12N bytes
    _Float16* whp = ws16;
    _Float16* wvp = ws16 + N;
    _Float16* cig = ws16 + 2 * N;
    _Float16* xg  = ws16 + 3 * N;
    _Float16* yhg = ws16 + 4 * N;
    _Float16* yvg = ws16 + 5 * N;

    pack_w<<<dim3((int)(N / 8 / 256)), dim3(256), 0, stream>>>(wg, whp, wvp);

    dim3 grid(W / TILE, H / TILE);              // 64 x 64 = 4096 blocks
    fused_pd<0><<<grid, dim3(NT), 0, stream>>>(img, whp, wvp, cig, xg, yhg, yvg, out);
    fused_pd<1><<<grid, dim3(NT), 0, stream>>>(img, whp, wvp, cig, xg, yhg, yvg, out);
}